// Round 5
// baseline (57.602 us; speedup 1.0000x reference)
//
#include <hip/hip_runtime.h>
#include <cmath>

// Problem constants: B=4, T=1, DIN=4096, DOUT=11008, RANK=512
constexpr int DIN  = 4096;
constexpr int DOUT = 11008;
constexpr int RANK = 512;
constexpr int NB   = 4;

constexpr int NCHUNK = 256;          // d-chunks for lr partials
constexpr int DCH    = DIN / NCHUNK; // 16 d's per chunk
constexpr int SPLITK = 2;
constexpr int KHALF4 = DIN / SPLITK / 4; // 512 float4 per k-half per batch

// ---------------------------------------------------------------------------
// Phase 1 (fused prep): xs[b][d] = x*mask -> ws;  xc = x*(1-mask) -> LDS;
// partial[chunk][b][r] = sum_{d in chunk} xc[b][d] * V[d][r]
// ---------------------------------------------------------------------------
__global__ __launch_bounds__(512)
void lr_partial_kernel(const float* __restrict__ x,
                       const float* __restrict__ scale,
                       const float* __restrict__ thp,
                       const float* __restrict__ V,
                       float* __restrict__ partial,
                       float* __restrict__ xs)
{
    __shared__ float xc[NB * DCH];
    const int chunk = blockIdx.x;
    const int t = threadIdx.x;
    const float th = thp[0];
    if (t < NB * DCH) {
        const int b = t / DCH, dd = t % DCH;
        const int d = chunk * DCH + dd;
        const float xv = x[b * DIN + d];
        const bool keep = fabsf(xv * scale[d]) > th; // mask==1 -> sparse path
        xc[t] = keep ? 0.f : xv;
        xs[b * DIN + d] = keep ? xv : 0.f;
    }
    __syncthreads();
    const int r = t; // 0..511
    float a0 = 0.f, a1 = 0.f, a2 = 0.f, a3 = 0.f;
    #pragma unroll
    for (int dd = 0; dd < DCH; ++dd) {
        const float v = V[(size_t)(chunk * DCH + dd) * RANK + r];
        a0 = fmaf(xc[0 * DCH + dd], v, a0);
        a1 = fmaf(xc[1 * DCH + dd], v, a1);
        a2 = fmaf(xc[2 * DCH + dd], v, a2);
        a3 = fmaf(xc[3 * DCH + dd], v, a3);
    }
    float* p = partial + (size_t)chunk * (NB * RANK) + r;
    p[0 * RANK] = a0;
    p[1 * RANK] = a1;
    p[2 * RANK] = a2;
    p[3 * RANK] = a3;
}

// ---------------------------------------------------------------------------
// Phase 2: lr[b][r] = S[r] * sum_chunk partial[chunk][b][r]
// 16 threads per output -> all 16 loads in flight, one latency round.
// ---------------------------------------------------------------------------
__global__ __launch_bounds__(256)
void lr_reduce_kernel(const float* __restrict__ partial,
                      const float* __restrict__ S,
                      float* __restrict__ lr)
{
    const int t = blockIdx.x * 256 + threadIdx.x;
    const int idx = t >> 4;  // output index 0..NB*RANK-1
    const int s = t & 15;    // chunk-subset
    float sum = 0.f;
    #pragma unroll
    for (int j = 0; j < 16; ++j)
        sum += partial[(size_t)(s * 16 + j) * (NB * RANK) + idx];
    #pragma unroll
    for (int m = 8; m >= 1; m >>= 1)
        sum += __shfl_xor(sum, m, 64);
    if (s == 0)
        lr[idx] = sum * S[idx & (RANK - 1)];
}

// ---------------------------------------------------------------------------
// Main (split-K=2, R=4 rows/wave, xs staged in LDS):
//   part[kh][b][o] = sum_{d in half kh} xs[b][d]*W[o][d]  (+ U.lr for kh==0)
// Block = 4 waves x 4 rows = 16 rows, one k-half. Inner loop VMEM = W only.
// LDS = 32 KB -> 5 blocks/CU; grid (688, 2).
// ---------------------------------------------------------------------------
__global__ __launch_bounds__(256)
void rsparse_main_kernel(const float* __restrict__ xs,
                         const float* __restrict__ W,
                         const float* __restrict__ U,
                         const float* __restrict__ lr,
                         float* __restrict__ part)
{
    __shared__ float4 sx4[NB * KHALF4]; // 32 KB: this k-half of xs, [b][512] float4
    const int tid = threadIdx.x;
    const int kh  = blockIdx.y;

    const float4* __restrict__ XSg = (const float4*)xs; // [NB][1024]
    #pragma unroll
    for (int i = tid; i < NB * KHALF4; i += 256) {
        const int b = i >> 9, j4 = i & (KHALF4 - 1);
        sx4[i] = XSg[b * (DIN / 4) + kh * KHALF4 + j4];
    }
    __syncthreads();

    const int wave = tid >> 6, lane = tid & 63;
    const int o0 = (blockIdx.x * 4 + wave) * 4; // 4 consecutive rows

    const float4* __restrict__ W0 = (const float4*)(W + (size_t)(o0 + 0) * DIN) + kh * KHALF4;
    const float4* __restrict__ W1 = (const float4*)(W + (size_t)(o0 + 1) * DIN) + kh * KHALF4;
    const float4* __restrict__ W2 = (const float4*)(W + (size_t)(o0 + 2) * DIN) + kh * KHALF4;
    const float4* __restrict__ W3 = (const float4*)(W + (size_t)(o0 + 3) * DIN) + kh * KHALF4;

    float acc[4][NB] = {};

    #pragma unroll 2
    for (int k = 0; k < 8; ++k) {
        const int c = (k << 6) + lane; // 0..511
        const float4 w0 = W0[c];
        const float4 w1 = W1[c];
        const float4 w2 = W2[c];
        const float4 w3 = W3[c];
        #pragma unroll
        for (int b = 0; b < NB; ++b) {
            const float4 xv = sx4[b * KHALF4 + c];
            acc[0][b] = fmaf(w0.x, xv.x, acc[0][b]);
            acc[0][b] = fmaf(w0.y, xv.y, acc[0][b]);
            acc[0][b] = fmaf(w0.z, xv.z, acc[0][b]);
            acc[0][b] = fmaf(w0.w, xv.w, acc[0][b]);
            acc[1][b] = fmaf(w1.x, xv.x, acc[1][b]);
            acc[1][b] = fmaf(w1.y, xv.y, acc[1][b]);
            acc[1][b] = fmaf(w1.z, xv.z, acc[1][b]);
            acc[1][b] = fmaf(w1.w, xv.w, acc[1][b]);
            acc[2][b] = fmaf(w2.x, xv.x, acc[2][b]);
            acc[2][b] = fmaf(w2.y, xv.y, acc[2][b]);
            acc[2][b] = fmaf(w2.z, xv.z, acc[2][b]);
            acc[2][b] = fmaf(w2.w, xv.w, acc[2][b]);
            acc[3][b] = fmaf(w3.x, xv.x, acc[3][b]);
            acc[3][b] = fmaf(w3.y, xv.y, acc[3][b]);
            acc[3][b] = fmaf(w3.z, xv.z, acc[3][b]);
            acc[3][b] = fmaf(w3.w, xv.w, acc[3][b]);
        }
    }

    if (kh == 0) { // U.lr term once per o-group
        const float4* __restrict__ U0 = (const float4*)(U + (size_t)(o0 + 0) * RANK);
        const float4* __restrict__ U1 = (const float4*)(U + (size_t)(o0 + 1) * RANK);
        const float4* __restrict__ U2 = (const float4*)(U + (size_t)(o0 + 2) * RANK);
        const float4* __restrict__ U3 = (const float4*)(U + (size_t)(o0 + 3) * RANK);
        const float4* __restrict__ LR = (const float4*)lr; // [NB][128]
        #pragma unroll
        for (int j = 0; j < 2; ++j) {
            const int c = (j << 6) + lane; // 0..127
            const float4 u0 = U0[c];
            const float4 u1 = U1[c];
            const float4 u2 = U2[c];
            const float4 u3 = U3[c];
            #pragma unroll
            for (int b = 0; b < NB; ++b) {
                const float4 lv = LR[b * 128 + c];
                acc[0][b] = fmaf(u0.x, lv.x, acc[0][b]);
                acc[0][b] = fmaf(u0.y, lv.y, acc[0][b]);
                acc[0][b] = fmaf(u0.z, lv.z, acc[0][b]);
                acc[0][b] = fmaf(u0.w, lv.w, acc[0][b]);
                acc[1][b] = fmaf(u1.x, lv.x, acc[1][b]);
                acc[1][b] = fmaf(u1.y, lv.y, acc[1][b]);
                acc[1][b] = fmaf(u1.z, lv.z, acc[1][b]);
                acc[1][b] = fmaf(u1.w, lv.w, acc[1][b]);
                acc[2][b] = fmaf(u2.x, lv.x, acc[2][b]);
                acc[2][b] = fmaf(u2.y, lv.y, acc[2][b]);
                acc[2][b] = fmaf(u2.z, lv.z, acc[2][b]);
                acc[2][b] = fmaf(u2.w, lv.w, acc[2][b]);
                acc[3][b] = fmaf(u3.x, lv.x, acc[3][b]);
                acc[3][b] = fmaf(u3.y, lv.y, acc[3][b]);
                acc[3][b] = fmaf(u3.z, lv.z, acc[3][b]);
                acc[3][b] = fmaf(u3.w, lv.w, acc[3][b]);
            }
        }
    }

    // 64-lane butterfly reduction
    #pragma unroll
    for (int r = 0; r < 4; ++r)
        #pragma unroll
        for (int b = 0; b < NB; ++b)
            #pragma unroll
            for (int m = 32; m >= 1; m >>= 1)
                acc[r][b] += __shfl_xor(acc[r][b], m, 64);

    if (lane == 0) {
        float* p = part + (size_t)kh * (NB * DOUT);
        #pragma unroll
        for (int r = 0; r < 4; ++r)
            #pragma unroll
            for (int b = 0; b < NB; ++b)
                p[b * DOUT + o0 + r] = acc[r][b];
    }
}

// ---------------------------------------------------------------------------
// Final: out[b][o] = part[0][b][o] + part[1][b][o] + bias[o]  (float4)
// grid = NB*DOUT/4/256 = 43 blocks
// ---------------------------------------------------------------------------
__global__ __launch_bounds__(256)
void final_add_kernel(const float* __restrict__ part,
                      const float* __restrict__ bias,
                      float* __restrict__ out)
{
    const int i4 = blockIdx.x * 256 + threadIdx.x; // float4 index, 0..NB*DOUT/4-1
    const int o4 = i4 % (DOUT / 4);
    const float4 p0 = ((const float4*)part)[i4];
    const float4 p1 = ((const float4*)part)[NB * DOUT / 4 + i4];
    const float4 bv = ((const float4*)bias)[o4];
    float4 r;
    r.x = p0.x + p1.x + bv.x;
    r.y = p0.y + p1.y + bv.y;
    r.z = p0.z + p1.z + bv.z;
    r.w = p0.w + p1.w + bv.w;
    ((float4*)out)[i4] = r;
}

// ---------------------------------------------------------------------------
extern "C" void kernel_launch(void* const* d_in, const int* in_sizes, int n_in,
                              void* d_out, int out_size, void* d_ws, size_t ws_size,
                              hipStream_t stream)
{
    const float* x     = (const float*)d_in[0]; // [4][1][4096]
    const float* W     = (const float*)d_in[1]; // [11008][4096]
    const float* bias  = (const float*)d_in[2]; // [11008]
    const float* U     = (const float*)d_in[3]; // [11008][512]
    const float* S     = (const float*)d_in[4]; // [512]
    const float* V     = (const float*)d_in[5]; // [4096][512]
    const float* scale = (const float*)d_in[6]; // [4096]
    const float* thp   = (const float*)d_in[7]; // [1]
    float* out = (float*)d_out;                 // [4][1][11008]

    float* partial = (float*)d_ws;                          // 2 MB
    float* lr      = partial + (size_t)NCHUNK * NB * RANK;  // 8 KB
    float* xs      = lr + NB * RANK;                        // 64 KB (16B-aligned)
    float* part    = xs + NB * DIN;                         // 352 KB

    lr_partial_kernel<<<NCHUNK, 512, 0, stream>>>(x, scale, thp, V, partial, xs);
    lr_reduce_kernel<<<(NB * RANK * 16) / 256, 256, 0, stream>>>(partial, S, lr);

    dim3 grid(DOUT / 16, SPLITK);
    rsparse_main_kernel<<<grid, 256, 0, stream>>>(xs, W, U, lr, part);
    final_add_kernel<<<(NB * DOUT / 4) / 256, 256, 0, stream>>>(part, bias, out);
}